// Round 1
// 645.734 us; speedup vs baseline: 1.1193x; 1.1193x over previous
//
#include <hip/hip_runtime.h>
#include <math.h>

typedef __attribute__((ext_vector_type(2))) float f32x2;
typedef __attribute__((ext_vector_type(4))) float f32x4;

// ---------- small vector helpers ----------
struct V3 { float x, y, z; };
__device__ __forceinline__ V3 v3(float a, float b, float c){ V3 r; r.x=a; r.y=b; r.z=c; return r; }
__device__ __forceinline__ V3 vsub(V3 a, V3 b){ return v3(a.x-b.x, a.y-b.y, a.z-b.z); }
__device__ __forceinline__ float vdot(V3 a, V3 b){ return a.x*b.x + a.y*b.y + a.z*b.z; }
__device__ __forceinline__ V3 vcross(V3 a, V3 b){
  return v3(a.y*b.z - a.z*b.y, a.z*b.x - a.x*b.z, a.x*b.y - a.y*b.x);
}
__device__ __forceinline__ V3 vunit(V3 a){            // reference _normalize: x / max(|x|, 1e-12)
  float n = sqrtf(vdot(a,a));
  float inv = 1.0f / fmaxf(n, 1e-12f);
  return v3(a.x*inv, a.y*inv, a.z*inv);
}
__device__ __forceinline__ float sgnf(float x){ return (x > 0.f) ? 1.f : ((x < 0.f) ? -1.f : 0.f); }
__device__ __forceinline__ float bcastf(float v, int lane){   // v_readlane (SGPR lane index ok)
  return __int_as_float(__builtin_amdgcn_readlane(__float_as_int(v), lane));
}

// ---------- setup: Gram matrices for analytic LayerNorm stats ----------
__global__ void setup_gram(const float* __restrict__ Wn, const float* __restrict__ bn,
                           const float* __restrict__ We, const float* __restrict__ be,
                           float* __restrict__ Ge, float* __restrict__ abarE,
                           float* __restrict__ Gn, float* __restrict__ abarN)
{
  int tid = threadIdx.x;
  if (tid < 576) {
    int i = tid / 24, j = tid % 24;
    const float* ai = (i < 23) ? (We + i * 128) : be;
    const float* aj = (j < 23) ? (We + j * 128) : be;
    float s = 0.f;
    for (int c = 0; c < 128; ++c) s += ai[c] * aj[c];
    Ge[tid] = s * (1.0f / 128.0f);
  } else if (tid < 601) {
    int t = tid - 576; int i = t / 5, j = t % 5;
    const float* ai = (i < 4) ? (Wn + i * 128) : bn;
    const float* aj = (j < 4) ? (Wn + j * 128) : bn;
    float s = 0.f;
    for (int c = 0; c < 128; ++c) s += ai[c] * aj[c];
    Gn[t] = s * (1.0f / 128.0f);
  } else if (tid < 625) {
    int k = tid - 601;
    const float* a = (k < 23) ? (We + k * 128) : be;
    float s = 0.f;
    for (int c = 0; c < 128; ++c) s += a[c];
    abarE[k] = s * (1.0f / 128.0f);
  } else if (tid < 630) {
    int k = tid - 625;
    const float* a = (k < 4) ? (Wn + k * 128) : bn;
    float s = 0.f;
    for (int c = 0; c < 128; ++c) s += a[c];
    abarN[k] = s * (1.0f / 128.0f);
  }
}

// ---------- node kernel: h_V + stage 12-float node records [Q(9), x, y, z] ----------
__global__ __launch_bounds__(256) void node_kernel(
    const float* __restrict__ X, const int* __restrict__ batch,
    const float* __restrict__ Wn, const float* __restrict__ bn,
    const float* __restrict__ gn, const float* __restrict__ betan,
    const float* __restrict__ Gn, const float* __restrict__ abarN,
    float* __restrict__ Qws, int* __restrict__ validws,
    float* __restrict__ outV, int N)
{
  int lane = threadIdx.x & 63;
  int wave = threadIdx.x >> 6;
  int base = blockIdx.x * 256 + wave * 64;
  int i = base + lane;
  bool live = (i < N);
  int ic = live ? i : (N - 1);

  int im1 = (ic >= 1) ? ic - 1 : 0;
  int ip1 = (ic + 1 < N) ? ic + 1 : N - 1;
  int ip2 = (ic + 2 < N) ? ic + 2 : N - 1;

  V3 xm1 = v3(X[3*im1], X[3*im1+1], X[3*im1+2]);
  V3 x0  = v3(X[3*ic ], X[3*ic +1], X[3*ic +2]);
  V3 xp1 = v3(X[3*ip1], X[3*ip1+1], X[3*ip1+2]);
  V3 xp2 = v3(X[3*ip2], X[3*ip2+1], X[3*ip2+2]);

  int b0 = batch[ic];
  bool bnd_i  = (ic >= 1)    && (batch[ic - 1] != b0);
  bool bnd_i1 = (ic + 1 < N) && (batch[ic + 1] != b0);
  bool bnd_i2 = (ic + 2 < N) && (batch[ic + 2] != batch[ic + 1]);

  bool bad_d = bnd_i || bnd_i1 || bnd_i2 || (ic == 0) || (ic >= N - 2);
  bool bad_a = bnd_i || bnd_i1 || (ic == 0) || (ic == N - 1);

  V3 u0 = vunit(vsub(x0,  xm1));   // U[i-1]
  V3 u1 = vunit(vsub(xp1, x0 ));   // U[i]
  V3 u2 = vunit(vsub(xp2, xp1));   // U[i+1]
  V3 c1 = vunit(vcross(u0, u1));
  V3 c2 = vunit(vcross(u1, u2));

  float cosd = vdot(c1, c2);
  cosd = fminf(fmaxf(cosd, -1.0f + 1e-6f), 1.0f - 1e-6f);
  float sd = vdot(c2, u0);
  float f0, f1;
  if (bad_d)          { f0 = 0.f; f1 = 0.f; }
  else {
    float sg = sgnf(sd);
    if (sg == 0.f)    { f0 = 0.f; f1 = 1.f; }
    else              { f0 = sg * sqrtf(fmaxf(1.f - cosd * cosd, 0.f)); f1 = cosd; }
  }

  V3 d0 = vunit(vsub(xm1, x0));
  V3 d1 = vunit(vsub(xp1, x0));
  float cosa = vdot(d0, d1);
  float sina = sqrtf(fmaxf(1.0f - cosa * cosa + 1e-6f, 0.f));
  float f2 = bad_a ? 0.f : sina;
  float f3 = bad_a ? 0.f : cosa;

  // local frame Q (columns: bvec, nvec, bvec x nvec), zeroed when bad_a
  V3 bv = vunit(vsub(u0, u1));
  V3 nv = c1;                       // == unit(cross(u0,u1))
  V3 tv = vcross(bv, nv);
  float q[9];
  if (bad_a) {
    #pragma unroll
    for (int k = 0; k < 9; ++k) q[k] = 0.f;
  } else {
    q[0]=bv.x; q[1]=nv.x; q[2]=tv.x;
    q[3]=bv.y; q[4]=nv.y; q[5]=tv.y;
    q[6]=bv.z; q[7]=nv.z; q[8]=tv.z;
  }
  if (live) {
    f32x4* qp = (f32x4*)(Qws + (size_t)i * 12);
    f32x4 ca; ca.x=q[0]; ca.y=q[1]; ca.z=q[2]; ca.w=q[3];
    f32x4 cb; cb.x=q[4]; cb.y=q[5]; cb.z=q[6]; cb.w=q[7];
    f32x4 cc; cc.x=q[8]; cc.y=x0.x; cc.z=x0.y; cc.w=x0.z;
    qp[0] = ca; qp[1] = cb; qp[2] = cc;
    validws[i] = bad_a ? 0 : 1;
  }

  // analytic LN stats: fa = [f0..f3, 1]
  float fa[5] = { f0, f1, f2, f3, 1.0f };
  float mmean = 0.f;
  #pragma unroll
  for (int k = 0; k < 5; ++k) mmean = fmaf(fa[k], abarN[k], mmean);
  float E2 = 0.f;
  #pragma unroll
  for (int ii = 0; ii < 5; ++ii) {
    float ti = 0.f;
    #pragma unroll
    for (int jj = 0; jj < 5; ++jj) ti = fmaf(Gn[ii * 5 + jj], fa[jj], ti);
    E2 = fmaf(fa[ii], ti, E2);
  }
  float var  = fmaxf(E2 - mmean * mmean, 0.f);
  float rstd = rsqrtf(var + 1e-5f);

  // per-lane output column pair (2*lane, 2*lane+1), packed fp32
  f32x2 W2[4];
  #pragma unroll
  for (int k = 0; k < 4; ++k) W2[k] = *(const f32x2*)(Wn + k * 128 + 2 * lane);
  f32x2 b2 = *(const f32x2*)(bn    + 2 * lane);
  f32x2 g2 = *(const f32x2*)(gn    + 2 * lane);
  f32x2 e2 = *(const f32x2*)(betan + 2 * lane);

  for (int t = 0; t < 64; ++t) {
    int node = base + t;
    if (node >= N) break;
    float bf0 = bcastf(f0, t), bf1 = bcastf(f1, t);
    float bf2 = bcastf(f2, t), bf3 = bcastf(f3, t);
    float bm  = bcastf(mmean, t), br = bcastf(rstd, t);
    f32x2 acc = b2;
    f32x2 s0 = bf0, s1 = bf1, s2 = bf2, s3 = bf3;
    acc = __builtin_elementwise_fma(s0, W2[0], acc);
    acc = __builtin_elementwise_fma(s1, W2[1], acc);
    acc = __builtin_elementwise_fma(s2, W2[2], acc);
    acc = __builtin_elementwise_fma(s3, W2[3], acc);
    f32x2 out;
    out.x = (acc.x - bm) * br * g2.x + e2.x;
    out.y = (acc.y - bm) * br * g2.y + e2.y;
    *(f32x2*)(outV + (size_t)node * 128 + 2 * lane) = out;
  }
}

// ---------- edge kernel ----------
// Phase 1 (lane = edge): vectorized node-record gathers, compute f[23] + LN stats,
//   stage {f[0..22], mean, rstd} into LDS as rotated float4 chunks (conflict-free).
// Phase 2 (lane = column pair): uniform ds_read_b128 broadcasts + v_pk_fma_f32,
//   one coalesced float2 store per edge.
__global__ __launch_bounds__(256) void edge_kernel(
    const int* __restrict__ eidx,
    const float* __restrict__ We, const float* __restrict__ be,
    const float* __restrict__ ge, const float* __restrict__ betae,
    const float* __restrict__ Qws, const int* __restrict__ validws,
    const float* __restrict__ Ge, const float* __restrict__ abarE,
    float* __restrict__ outE, int N, int E)
{
  __shared__ float smem[256 * 32];       // 32 KB: 256 rows x 8 float4 slots

  int lane = threadIdx.x & 63;
  int wave = threadIdx.x >> 6;
  int base = blockIdx.x * 256 + wave * 64;
  int e = base + lane;
  int ec = (e < E) ? e : (E - 1);

  int s = eidx[ec];
  int t = eidx[E + ec];

  const f32x4* sp = (const f32x4*)(Qws + (size_t)s * 12);
  const f32x4* tp = (const f32x4*)(Qws + (size_t)t * 12);
  f32x4 sA = sp[0], sB = sp[1], sC = sp[2];
  f32x4 tA = tp[0], tB = tp[1], tC = tp[2];

  float Qs[9] = { sA.x, sA.y, sA.z, sA.w, sB.x, sB.y, sB.z, sB.w, sC.x };
  float Qt[9] = { tA.x, tA.y, tA.z, tA.w, tB.x, tB.y, tB.z, tB.w, tC.x };
  float Xs0 = sC.y, Xs1 = sC.z, Xs2 = sC.w;
  float Xt0 = tC.y, Xt1 = tC.z, Xt2 = tC.w;
  int ok = validws[s] & validws[t];

  // R = Qt^T * Qs ;  R[i][k] = sum_j Qt[3j+i]*Qs[3j+k]
  float R[9];
  #pragma unroll
  for (int i = 0; i < 3; ++i) {
    #pragma unroll
    for (int k = 0; k < 3; ++k) {
      R[3*i+k] = Qt[i] * Qs[k] + Qt[3+i] * Qs[3+k] + Qt[6+i] * Qs[6+k];
    }
  }

  float Rxx = R[0], Ryy = R[4], Rzz = R[8];
  float m0 = 0.5f * sqrtf(fabsf(1.f + Rxx - Ryy - Rzz));
  float m1 = 0.5f * sqrtf(fabsf(1.f - Rxx + Ryy - Rzz));
  float m2 = 0.5f * sqrtf(fabsf(1.f - Rxx - Ryy + Rzz));
  float s0 = sgnf(R[7] - R[5]);   // R21 - R12
  float s1 = sgnf(R[2] - R[6]);   // R02 - R20
  float s2 = sgnf(R[3] - R[1]);   // R10 - R01
  float w  = 0.5f * sqrtf(fmaxf(1.f + Rxx + Ryy + Rzz, 0.f));
  float q0 = s0 * m0, q1 = s1 * m1, q2 = s2 * m2;
  float qn = fmaxf(sqrtf(q0*q0 + q1*q1 + q2*q2 + w*w), 1e-12f);
  float qinv = 1.0f / qn;
  float msk = ok ? 1.f : 0.f;

  float f[23];
  f[0] = q0 * qinv * msk; f[1] = q1 * qinv * msk;
  f[2] = q2 * qinv * msk; f[3] = w  * qinv * msk;

  float dx = Xs0 - Xt0, dy = Xs1 - Xt1, dz = Xs2 - Xt2;
  float d2 = dx*dx + dy*dy + dz*dz;
  float dist = sqrtf(d2 + 1e-6f);
  #pragma unroll
  for (int k = 0; k < 16; ++k) {
    float u = (dist - (float)k * (20.0f / 15.0f)) * 0.8f;
    f[4 + k] = __expf(-u * u);
  }
  float dn = fmaxf(sqrtf(d2), 1e-12f);
  float rinv = 1.0f / dn;
  float ux = dx * rinv, uy = dy * rinv, uz = dz * rinv;
  // direct = Qt^T * u  (Qt rows are zero when tgt invalid -> already masked)
  f[20] = Qt[0]*ux + Qt[3]*uy + Qt[6]*uz;
  f[21] = Qt[1]*ux + Qt[4]*uy + Qt[7]*uz;
  f[22] = Qt[2]*ux + Qt[5]*uy + Qt[8]*uz;

  // analytic LN stats (fa = [f, 1]); Ge/abarE loads are wave-uniform -> scalar path
  float mmean = abarE[23];
  #pragma unroll
  for (int k = 0; k < 23; ++k) mmean = fmaf(f[k], abarE[k], mmean);
  float E2 = 0.f;
  #pragma unroll
  for (int ii = 0; ii < 24; ++ii) {
    float fi = (ii < 23) ? f[ii] : 1.0f;
    float ti = 0.f;
    #pragma unroll
    for (int jj = 0; jj < 24; ++jj) {
      float fj = (jj < 23) ? f[jj] : 1.0f;
      ti = fmaf(Ge[ii * 24 + jj], fj, ti);
    }
    E2 = fmaf(fi, ti, E2);
  }
  float var  = fmaxf(E2 - mmean * mmean, 0.f);
  float rstd = rsqrtf(var + 1e-5f);

  // stage broadcast payload into LDS: 7 float4 chunks, rotated by (lane&7) so the
  // 64-lane b128 writes spread across all 32 banks; reads are row-uniform broadcasts.
  {
    float ch[28];
    #pragma unroll
    for (int k = 0; k < 23; ++k) ch[k] = f[k];
    ch[23] = mmean; ch[24] = rstd; ch[25] = 0.f; ch[26] = 0.f; ch[27] = 0.f;
    f32x4* rowp = (f32x4*)(smem + (int)threadIdx.x * 32);
    int rot = lane & 7;
    #pragma unroll
    for (int c = 0; c < 7; ++c) {
      f32x4 v; v.x = ch[4*c]; v.y = ch[4*c+1]; v.z = ch[4*c+2]; v.w = ch[4*c+3];
      rowp[(c + rot) & 7] = v;
    }
  }
  __syncthreads();

  // per-lane output column pair (persist in VGPRs across the broadcast loop)
  f32x2 Wc[23];
  #pragma unroll
  for (int k = 0; k < 23; ++k) Wc[k] = *(const f32x2*)(We + k * 128 + 2 * lane);
  f32x2 b2 = *(const f32x2*)(be    + 2 * lane);
  f32x2 g2 = *(const f32x2*)(ge    + 2 * lane);
  f32x2 e2 = *(const f32x2*)(betae + 2 * lane);

  #pragma unroll 2
  for (int tt = 0; tt < 64; ++tt) {
    int ee = base + tt;
    if (ee >= E) break;
    const f32x4* rp = (const f32x4*)(smem + (wave * 64 + tt) * 32);
    int rot2 = tt & 7;
    float fs[28];
    #pragma unroll
    for (int c = 0; c < 7; ++c) {
      f32x4 v = rp[(c + rot2) & 7];
      fs[4*c] = v.x; fs[4*c+1] = v.y; fs[4*c+2] = v.z; fs[4*c+3] = v.w;
    }
    float bm = fs[23], br = fs[24];
    f32x2 acc = b2;
    #pragma unroll
    for (int k = 0; k < 23; ++k) {
      f32x2 sv = fs[k];                              // splat -> v_pk_fma_f32
      acc = __builtin_elementwise_fma(sv, Wc[k], acc);
    }
    f32x2 out;
    out.x = (acc.x - bm) * br * g2.x + e2.x;
    out.y = (acc.y - bm) * br * g2.y + e2.y;
    *(f32x2*)(outE + (size_t)ee * 128 + 2 * lane) = out;
  }
}

// ---------- launcher ----------
extern "C" void kernel_launch(void* const* d_in, const int* in_sizes, int n_in,
                              void* d_out, int out_size, void* d_ws, size_t ws_size,
                              hipStream_t stream)
{
  const float* X     = (const float*)d_in[0];
  const int*   batch = (const int*)  d_in[1];
  const int*   eidx  = (const int*)  d_in[2];
  const float* Wn    = (const float*)d_in[3];
  const float* bn    = (const float*)d_in[4];
  const float* gn    = (const float*)d_in[5];
  const float* betan = (const float*)d_in[6];
  const float* We    = (const float*)d_in[7];
  const float* be    = (const float*)d_in[8];
  const float* ge    = (const float*)d_in[9];
  const float* betae = (const float*)d_in[10];

  int N = in_sizes[0] / 3;
  int E = in_sizes[2] / 2;

  float* ws      = (float*)d_ws;
  float* Qws     = ws;                                  // N*12 floats (16B-aligned rows)
  int*   validws = (int*)(ws + (size_t)N * 12);         // N ints
  float* Ge      = ws + (size_t)N * 12 + N;             // 576
  float* abarE   = Ge + 576;                            // 24
  float* Gn      = abarE + 24;                          // 25
  float* abarN   = Gn + 25;                             // 5

  float* outV = (float*)d_out;
  float* outE = outV + (size_t)N * 128;

  hipLaunchKernelGGL(setup_gram, dim3(1), dim3(640), 0, stream,
                     Wn, bn, We, be, Ge, abarE, Gn, abarN);

  int nblocks = (N + 255) / 256;
  hipLaunchKernelGGL(node_kernel, dim3(nblocks), dim3(256), 0, stream,
                     X, batch, Wn, bn, gn, betan, Gn, abarN, Qws, validws, outV, N);

  int eblocks = (E + 255) / 256;
  hipLaunchKernelGGL(edge_kernel, dim3(eblocks), dim3(256), 0, stream,
                     eidx, We, be, ge, betae, Qws, validws, Ge, abarE, outE, N, E);
}

// Round 2
// 631.579 us; speedup vs baseline: 1.1444x; 1.0224x over previous
//
#include <hip/hip_runtime.h>
#include <math.h>

typedef __attribute__((ext_vector_type(2))) float f32x2;
typedef __attribute__((ext_vector_type(4))) float f32x4;

// ---------- small vector helpers ----------
struct V3 { float x, y, z; };
__device__ __forceinline__ V3 v3(float a, float b, float c){ V3 r; r.x=a; r.y=b; r.z=c; return r; }
__device__ __forceinline__ V3 vsub(V3 a, V3 b){ return v3(a.x-b.x, a.y-b.y, a.z-b.z); }
__device__ __forceinline__ float vdot(V3 a, V3 b){ return a.x*b.x + a.y*b.y + a.z*b.z; }
__device__ __forceinline__ V3 vcross(V3 a, V3 b){
  return v3(a.y*b.z - a.z*b.y, a.z*b.x - a.x*b.z, a.x*b.y - a.y*b.x);
}
__device__ __forceinline__ V3 vunit(V3 a){            // reference _normalize: x / max(|x|, 1e-12)
  float n = sqrtf(vdot(a,a));
  float inv = 1.0f / fmaxf(n, 1e-12f);
  return v3(a.x*inv, a.y*inv, a.z*inv);
}
__device__ __forceinline__ float sgnf(float x){ return (x > 0.f) ? 1.f : ((x < 0.f) ? -1.f : 0.f); }

// ---------- setup: Gram matrices for analytic LayerNorm stats ----------
__global__ void setup_gram(const float* __restrict__ Wn, const float* __restrict__ bn,
                           const float* __restrict__ We, const float* __restrict__ be,
                           float* __restrict__ Ge, float* __restrict__ abarE,
                           float* __restrict__ Gn, float* __restrict__ abarN)
{
  int tid = threadIdx.x;
  if (tid < 576) {
    int i = tid / 24, j = tid % 24;
    const float* ai = (i < 23) ? (We + i * 128) : be;
    const float* aj = (j < 23) ? (We + j * 128) : be;
    float s = 0.f;
    for (int c = 0; c < 128; ++c) s += ai[c] * aj[c];
    Ge[tid] = s * (1.0f / 128.0f);
  } else if (tid < 601) {
    int t = tid - 576; int i = t / 5, j = t % 5;
    const float* ai = (i < 4) ? (Wn + i * 128) : bn;
    const float* aj = (j < 4) ? (Wn + j * 128) : bn;
    float s = 0.f;
    for (int c = 0; c < 128; ++c) s += ai[c] * aj[c];
    Gn[t] = s * (1.0f / 128.0f);
  } else if (tid < 625) {
    int k = tid - 601;
    const float* a = (k < 23) ? (We + k * 128) : be;
    float s = 0.f;
    for (int c = 0; c < 128; ++c) s += a[c];
    abarE[k] = s * (1.0f / 128.0f);
  } else if (tid < 630) {
    int k = tid - 625;
    const float* a = (k < 4) ? (Wn + k * 128) : bn;
    float s = 0.f;
    for (int c = 0; c < 128; ++c) s += a[c];
    abarN[k] = s * (1.0f / 128.0f);
  }
}

// ---------- node kernel: h_V + stage 12-float node records [Q(9), x, y, z] ----------
// Phase 2 broadcast via LDS (stride-8 rows, uniform ds_read_b128 with imm offsets).
__global__ __launch_bounds__(256, 4) void node_kernel(
    const float* __restrict__ X, const int* __restrict__ batch,
    const float* __restrict__ Wn, const float* __restrict__ bn,
    const float* __restrict__ gn, const float* __restrict__ betan,
    const float* __restrict__ Gn, const float* __restrict__ abarN,
    float* __restrict__ Qws, int* __restrict__ validws,
    float* __restrict__ outV, int N)
{
  __shared__ float smem[256 * 8];      // 8 KB: per-thread row of 8 floats

  int lane = threadIdx.x & 63;
  int wave = threadIdx.x >> 6;
  int base = blockIdx.x * 256 + wave * 64;
  int i = base + lane;
  bool live = (i < N);
  int ic = live ? i : (N - 1);

  int im1 = (ic >= 1) ? ic - 1 : 0;
  int ip1 = (ic + 1 < N) ? ic + 1 : N - 1;
  int ip2 = (ic + 2 < N) ? ic + 2 : N - 1;

  V3 xm1 = v3(X[3*im1], X[3*im1+1], X[3*im1+2]);
  V3 x0  = v3(X[3*ic ], X[3*ic +1], X[3*ic +2]);
  V3 xp1 = v3(X[3*ip1], X[3*ip1+1], X[3*ip1+2]);
  V3 xp2 = v3(X[3*ip2], X[3*ip2+1], X[3*ip2+2]);

  int b0 = batch[ic];
  bool bnd_i  = (ic >= 1)    && (batch[ic - 1] != b0);
  bool bnd_i1 = (ic + 1 < N) && (batch[ic + 1] != b0);
  bool bnd_i2 = (ic + 2 < N) && (batch[ic + 2] != batch[ic + 1]);

  bool bad_d = bnd_i || bnd_i1 || bnd_i2 || (ic == 0) || (ic >= N - 2);
  bool bad_a = bnd_i || bnd_i1 || (ic == 0) || (ic == N - 1);

  V3 u0 = vunit(vsub(x0,  xm1));   // U[i-1]
  V3 u1 = vunit(vsub(xp1, x0 ));   // U[i]
  V3 u2 = vunit(vsub(xp2, xp1));   // U[i+1]
  V3 c1 = vunit(vcross(u0, u1));
  V3 c2 = vunit(vcross(u1, u2));

  float cosd = vdot(c1, c2);
  cosd = fminf(fmaxf(cosd, -1.0f + 1e-6f), 1.0f - 1e-6f);
  float sd = vdot(c2, u0);
  float f0, f1;
  if (bad_d)          { f0 = 0.f; f1 = 0.f; }
  else {
    float sg = sgnf(sd);
    if (sg == 0.f)    { f0 = 0.f; f1 = 1.f; }
    else              { f0 = sg * sqrtf(fmaxf(1.f - cosd * cosd, 0.f)); f1 = cosd; }
  }

  V3 d0 = vunit(vsub(xm1, x0));
  V3 d1 = vunit(vsub(xp1, x0));
  float cosa = vdot(d0, d1);
  float sina = sqrtf(fmaxf(1.0f - cosa * cosa + 1e-6f, 0.f));
  float f2 = bad_a ? 0.f : sina;
  float f3 = bad_a ? 0.f : cosa;

  // local frame Q (columns: bvec, nvec, bvec x nvec), zeroed when bad_a
  V3 bv = vunit(vsub(u0, u1));
  V3 nv = c1;                       // == unit(cross(u0,u1))
  V3 tv = vcross(bv, nv);
  float q[9];
  if (bad_a) {
    #pragma unroll
    for (int k = 0; k < 9; ++k) q[k] = 0.f;
  } else {
    q[0]=bv.x; q[1]=nv.x; q[2]=tv.x;
    q[3]=bv.y; q[4]=nv.y; q[5]=tv.y;
    q[6]=bv.z; q[7]=nv.z; q[8]=tv.z;
  }
  if (live) {
    f32x4* qp = (f32x4*)(Qws + (size_t)i * 12);
    f32x4 ca; ca.x=q[0]; ca.y=q[1]; ca.z=q[2]; ca.w=q[3];
    f32x4 cb; cb.x=q[4]; cb.y=q[5]; cb.z=q[6]; cb.w=q[7];
    f32x4 cc; cc.x=q[8]; cc.y=x0.x; cc.z=x0.y; cc.w=x0.z;
    qp[0] = ca; qp[1] = cb; qp[2] = cc;
    validws[i] = bad_a ? 0 : 1;
  }

  // analytic LN stats: fa = [f0..f3, 1]
  float fa[5] = { f0, f1, f2, f3, 1.0f };
  float mmean = 0.f;
  #pragma unroll
  for (int k = 0; k < 5; ++k) mmean = fmaf(fa[k], abarN[k], mmean);
  float E2 = 0.f;
  #pragma unroll
  for (int ii = 0; ii < 5; ++ii) {
    float ti = 0.f;
    #pragma unroll
    for (int jj = 0; jj < 5; ++jj) ti = fmaf(Gn[ii * 5 + jj], fa[jj], ti);
    E2 = fmaf(fa[ii], ti, E2);
  }
  float var  = fmaxf(E2 - mmean * mmean, 0.f);
  float rstd = rsqrtf(var + 1e-5f);

  // stage broadcast payload: [f0,f1,f2,f3,mean,rstd,0,0] per thread (2x b128 writes)
  {
    f32x4* rowp = (f32x4*)(smem + (int)threadIdx.x * 8);
    f32x4 v0; v0.x = f0; v0.y = f1; v0.z = f2; v0.w = f3;
    f32x4 v1; v1.x = mmean; v1.y = rstd; v1.z = 0.f; v1.w = 0.f;
    rowp[0] = v0; rowp[1] = v1;
  }

  // per-lane output column pair (2*lane, 2*lane+1), packed fp32
  f32x2 W2[4];
  #pragma unroll
  for (int k = 0; k < 4; ++k) W2[k] = *(const f32x2*)(Wn + k * 128 + 2 * lane);
  f32x2 b2 = *(const f32x2*)(bn    + 2 * lane);
  f32x2 g2 = *(const f32x2*)(gn    + 2 * lane);
  f32x2 e2 = *(const f32x2*)(betan + 2 * lane);

  __syncthreads();

  int nIt = N - base; nIt = (nIt > 64) ? 64 : nIt;
  const float* rp = smem + (wave * 64) * 8;
  float* op = outV + (size_t)base * 128 + 2 * lane;
  #pragma unroll 2
  for (int t = 0; t < nIt; ++t) {
    f32x4 v0 = *(const f32x4*)(rp + 0);
    f32x4 v1 = *(const f32x4*)(rp + 4);
    float bm = v1.x, br = v1.y;
    f32x2 acc = b2;
    f32x2 s0 = v0.x, s1 = v0.y, s2 = v0.z, s3 = v0.w;
    acc = __builtin_elementwise_fma(s0, W2[0], acc);
    acc = __builtin_elementwise_fma(s1, W2[1], acc);
    acc = __builtin_elementwise_fma(s2, W2[2], acc);
    acc = __builtin_elementwise_fma(s3, W2[3], acc);
    f32x2 out;
    out.x = (acc.x - bm) * br * g2.x + e2.x;
    out.y = (acc.y - bm) * br * g2.y + e2.y;
    *(f32x2*)op = out;
    rp += 8; op += 128;
  }
}

// ---------- edge kernel ----------
// Phase 1 (lane = edge): vectorized node-record gathers, compute f[23] + LN stats,
//   stage {f[0..22], mean, rstd} into LDS rows of stride 36 floats (padding kills
//   write bank conflicts down to 8-way on 7 insts; reads are uniform broadcasts
//   with compile-time immediate offsets — zero per-iteration address math).
// Phase 2 (lane = column pair): uniform ds_read_b128 + v_pk_fma_f32,
//   one coalesced float2 store per edge.
__global__ __launch_bounds__(256, 4) void edge_kernel(
    const int* __restrict__ eidx,
    const float* __restrict__ We, const float* __restrict__ be,
    const float* __restrict__ ge, const float* __restrict__ betae,
    const float* __restrict__ Qws, const int* __restrict__ validws,
    const float* __restrict__ Ge, const float* __restrict__ abarE,
    float* __restrict__ outE, int N, int E)
{
  __shared__ float smem[256 * 36];       // 36 KB: 256 rows x 36 floats (28 used + pad)

  int lane = threadIdx.x & 63;
  int wave = threadIdx.x >> 6;
  int base = blockIdx.x * 256 + wave * 64;
  int e = base + lane;
  int ec = (e < E) ? e : (E - 1);

  int s = eidx[ec];
  int t = eidx[E + ec];

  const f32x4* sp = (const f32x4*)(Qws + (size_t)s * 12);
  const f32x4* tp = (const f32x4*)(Qws + (size_t)t * 12);
  f32x4 sA = sp[0], sB = sp[1], sC = sp[2];
  f32x4 tA = tp[0], tB = tp[1], tC = tp[2];

  float Qs[9] = { sA.x, sA.y, sA.z, sA.w, sB.x, sB.y, sB.z, sB.w, sC.x };
  float Qt[9] = { tA.x, tA.y, tA.z, tA.w, tB.x, tB.y, tB.z, tB.w, tC.x };
  float Xs0 = sC.y, Xs1 = sC.z, Xs2 = sC.w;
  float Xt0 = tC.y, Xt1 = tC.z, Xt2 = tC.w;
  int ok = validws[s] & validws[t];

  // R = Qt^T * Qs ;  R[i][k] = sum_j Qt[3j+i]*Qs[3j+k]
  float R[9];
  #pragma unroll
  for (int i = 0; i < 3; ++i) {
    #pragma unroll
    for (int k = 0; k < 3; ++k) {
      R[3*i+k] = Qt[i] * Qs[k] + Qt[3+i] * Qs[3+k] + Qt[6+i] * Qs[6+k];
    }
  }

  float Rxx = R[0], Ryy = R[4], Rzz = R[8];
  float m0 = 0.5f * sqrtf(fabsf(1.f + Rxx - Ryy - Rzz));
  float m1 = 0.5f * sqrtf(fabsf(1.f - Rxx + Ryy - Rzz));
  float m2 = 0.5f * sqrtf(fabsf(1.f - Rxx - Ryy + Rzz));
  float s0 = sgnf(R[7] - R[5]);   // R21 - R12
  float s1 = sgnf(R[2] - R[6]);   // R02 - R20
  float s2 = sgnf(R[3] - R[1]);   // R10 - R01
  float w  = 0.5f * sqrtf(fmaxf(1.f + Rxx + Ryy + Rzz, 0.f));
  float q0 = s0 * m0, q1 = s1 * m1, q2 = s2 * m2;
  float qn = fmaxf(sqrtf(q0*q0 + q1*q1 + q2*q2 + w*w), 1e-12f);
  float qinv = 1.0f / qn;
  float msk = ok ? 1.f : 0.f;

  float f[23];
  f[0] = q0 * qinv * msk; f[1] = q1 * qinv * msk;
  f[2] = q2 * qinv * msk; f[3] = w  * qinv * msk;

  float dx = Xs0 - Xt0, dy = Xs1 - Xt1, dz = Xs2 - Xt2;
  float d2 = dx*dx + dy*dy + dz*dz;
  float dist = sqrtf(d2 + 1e-6f);
  #pragma unroll
  for (int k = 0; k < 16; ++k) {
    float u = (dist - (float)k * (20.0f / 15.0f)) * 0.8f;
    f[4 + k] = __expf(-u * u);
  }
  float dn = fmaxf(sqrtf(d2), 1e-12f);
  float rinv = 1.0f / dn;
  float ux = dx * rinv, uy = dy * rinv, uz = dz * rinv;
  // direct = Qt^T * u  (Qt rows are zero when tgt invalid -> already masked)
  f[20] = Qt[0]*ux + Qt[3]*uy + Qt[6]*uz;
  f[21] = Qt[1]*ux + Qt[4]*uy + Qt[7]*uz;
  f[22] = Qt[2]*ux + Qt[5]*uy + Qt[8]*uz;

  // analytic LN stats (fa = [f, 1]); Ge/abarE loads are wave-uniform -> scalar path
  float mmean = abarE[23];
  #pragma unroll
  for (int k = 0; k < 23; ++k) mmean = fmaf(f[k], abarE[k], mmean);
  float E2 = 0.f;
  #pragma unroll
  for (int ii = 0; ii < 24; ++ii) {
    float fi = (ii < 23) ? f[ii] : 1.0f;
    float ti = 0.f;
    #pragma unroll
    for (int jj = 0; jj < 24; ++jj) {
      float fj = (jj < 23) ? f[jj] : 1.0f;
      ti = fmaf(Ge[ii * 24 + jj], fj, ti);
    }
    E2 = fmaf(fi, ti, E2);
  }
  float var  = fmaxf(E2 - mmean * mmean, 0.f);
  float rstd = rsqrtf(var + 1e-5f);

  // stage broadcast payload: 7 b128 writes into padded row (stride 36 floats)
  {
    f32x4* rowp = (f32x4*)(smem + (int)threadIdx.x * 36);
    f32x4 v;
    v.x = f[0];  v.y = f[1];  v.z = f[2];  v.w = f[3];  rowp[0] = v;
    v.x = f[4];  v.y = f[5];  v.z = f[6];  v.w = f[7];  rowp[1] = v;
    v.x = f[8];  v.y = f[9];  v.z = f[10]; v.w = f[11]; rowp[2] = v;
    v.x = f[12]; v.y = f[13]; v.z = f[14]; v.w = f[15]; rowp[3] = v;
    v.x = f[16]; v.y = f[17]; v.z = f[18]; v.w = f[19]; rowp[4] = v;
    v.x = f[20]; v.y = f[21]; v.z = f[22]; v.w = mmean; rowp[5] = v;
    v.x = rstd;  v.y = 0.f;   v.z = 0.f;   v.w = 0.f;   rowp[6] = v;
  }

  // per-lane output column pair (issue loads before the barrier so they overlap it)
  f32x2 Wc[23];
  #pragma unroll
  for (int k = 0; k < 23; ++k) Wc[k] = *(const f32x2*)(We + k * 128 + 2 * lane);
  f32x2 b2 = *(const f32x2*)(be    + 2 * lane);
  f32x2 g2 = *(const f32x2*)(ge    + 2 * lane);
  f32x2 e2 = *(const f32x2*)(betae + 2 * lane);

  __syncthreads();

  int nIt = E - base; nIt = (nIt > 64) ? 64 : nIt;
  const float* rp = smem + (wave * 64) * 36;
  float* op = outE + (size_t)base * 128 + 2 * lane;
  #pragma unroll 2
  for (int tt = 0; tt < nIt; ++tt) {
    f32x4 c0 = *(const f32x4*)(rp + 0);
    f32x4 c1 = *(const f32x4*)(rp + 4);
    f32x4 c2 = *(const f32x4*)(rp + 8);
    f32x4 c3 = *(const f32x4*)(rp + 12);
    f32x4 c4 = *(const f32x4*)(rp + 16);
    f32x4 c5 = *(const f32x4*)(rp + 20);
    f32x4 c6 = *(const f32x4*)(rp + 24);
    float fs[23] = { c0.x, c0.y, c0.z, c0.w,
                     c1.x, c1.y, c1.z, c1.w,
                     c2.x, c2.y, c2.z, c2.w,
                     c3.x, c3.y, c3.z, c3.w,
                     c4.x, c4.y, c4.z, c4.w,
                     c5.x, c5.y, c5.z };
    float bm = c5.w, br = c6.x;
    f32x2 acc = b2;
    #pragma unroll
    for (int k = 0; k < 23; ++k) {
      f32x2 sv = fs[k];                              // splat -> v_pk_fma_f32
      acc = __builtin_elementwise_fma(sv, Wc[k], acc);
    }
    f32x2 out;
    out.x = (acc.x - bm) * br * g2.x + e2.x;
    out.y = (acc.y - bm) * br * g2.y + e2.y;
    *(f32x2*)op = out;
    rp += 36; op += 128;
  }
}

// ---------- launcher ----------
extern "C" void kernel_launch(void* const* d_in, const int* in_sizes, int n_in,
                              void* d_out, int out_size, void* d_ws, size_t ws_size,
                              hipStream_t stream)
{
  const float* X     = (const float*)d_in[0];
  const int*   batch = (const int*)  d_in[1];
  const int*   eidx  = (const int*)  d_in[2];
  const float* Wn    = (const float*)d_in[3];
  const float* bn    = (const float*)d_in[4];
  const float* gn    = (const float*)d_in[5];
  const float* betan = (const float*)d_in[6];
  const float* We    = (const float*)d_in[7];
  const float* be    = (const float*)d_in[8];
  const float* ge    = (const float*)d_in[9];
  const float* betae = (const float*)d_in[10];

  int N = in_sizes[0] / 3;
  int E = in_sizes[2] / 2;

  float* ws      = (float*)d_ws;
  float* Qws     = ws;                                  // N*12 floats (16B-aligned rows)
  int*   validws = (int*)(ws + (size_t)N * 12);         // N ints
  float* Ge      = ws + (size_t)N * 12 + N;             // 576
  float* abarE   = Ge + 576;                            // 24
  float* Gn      = abarE + 24;                          // 25
  float* abarN   = Gn + 25;                             // 5

  float* outV = (float*)d_out;
  float* outE = outV + (size_t)N * 128;

  hipLaunchKernelGGL(setup_gram, dim3(1), dim3(640), 0, stream,
                     Wn, bn, We, be, Ge, abarE, Gn, abarN);

  int nblocks = (N + 255) / 256;
  hipLaunchKernelGGL(node_kernel, dim3(nblocks), dim3(256), 0, stream,
                     X, batch, Wn, bn, gn, betan, Gn, abarN, Qws, validws, outV, N);

  int eblocks = (E + 255) / 256;
  hipLaunchKernelGGL(edge_kernel, dim3(eblocks), dim3(256), 0, stream,
                     eidx, We, be, ge, betae, Qws, validws, Ge, abarE, outE, N, E);
}

// Round 3
// 625.924 us; speedup vs baseline: 1.1547x; 1.0090x over previous
//
#include <hip/hip_runtime.h>
#include <math.h>

typedef __attribute__((ext_vector_type(2))) float f32x2;
typedef __attribute__((ext_vector_type(4))) float f32x4;

// ---------- small vector helpers ----------
struct V3 { float x, y, z; };
__device__ __forceinline__ V3 v3(float a, float b, float c){ V3 r; r.x=a; r.y=b; r.z=c; return r; }
__device__ __forceinline__ V3 vsub(V3 a, V3 b){ return v3(a.x-b.x, a.y-b.y, a.z-b.z); }
__device__ __forceinline__ float vdot(V3 a, V3 b){ return a.x*b.x + a.y*b.y + a.z*b.z; }
__device__ __forceinline__ V3 vcross(V3 a, V3 b){
  return v3(a.y*b.z - a.z*b.y, a.z*b.x - a.x*b.z, a.x*b.y - a.y*b.x);
}
__device__ __forceinline__ V3 vunit(V3 a){            // reference _normalize: x / max(|x|, 1e-12)
  float n = sqrtf(vdot(a,a));
  float inv = 1.0f / fmaxf(n, 1e-12f);
  return v3(a.x*inv, a.y*inv, a.z*inv);
}
__device__ __forceinline__ float sgnf(float x){ return (x > 0.f) ? 1.f : ((x < 0.f) ? -1.f : 0.f); }

// ---------- setup: Gram matrices for analytic LayerNorm stats ----------
__global__ void setup_gram(const float* __restrict__ Wn, const float* __restrict__ bn,
                           const float* __restrict__ We, const float* __restrict__ be,
                           float* __restrict__ Ge, float* __restrict__ abarE,
                           float* __restrict__ Gn, float* __restrict__ abarN)
{
  int tid = threadIdx.x;
  if (tid < 576) {
    int i = tid / 24, j = tid % 24;
    const float* ai = (i < 23) ? (We + i * 128) : be;
    const float* aj = (j < 23) ? (We + j * 128) : be;
    float s = 0.f;
    for (int c = 0; c < 128; ++c) s += ai[c] * aj[c];
    Ge[tid] = s * (1.0f / 128.0f);
  } else if (tid < 601) {
    int t = tid - 576; int i = t / 5, j = t % 5;
    const float* ai = (i < 4) ? (Wn + i * 128) : bn;
    const float* aj = (j < 4) ? (Wn + j * 128) : bn;
    float s = 0.f;
    for (int c = 0; c < 128; ++c) s += ai[c] * aj[c];
    Gn[t] = s * (1.0f / 128.0f);
  } else if (tid < 625) {
    int k = tid - 601;
    const float* a = (k < 23) ? (We + k * 128) : be;
    float s = 0.f;
    for (int c = 0; c < 128; ++c) s += a[c];
    abarE[k] = s * (1.0f / 128.0f);
  } else if (tid < 630) {
    int k = tid - 625;
    const float* a = (k < 4) ? (Wn + k * 128) : bn;
    float s = 0.f;
    for (int c = 0; c < 128; ++c) s += a[c];
    abarN[k] = s * (1.0f / 128.0f);
  }
}

// ---------- node kernel: h_V + stage 12-float node records [Q(9), x, y, z] ----------
// Phase 2 broadcast via LDS (stride-8 rows, uniform ds_read_b128 with imm offsets).
__global__ __launch_bounds__(256, 4) void node_kernel(
    const float* __restrict__ X, const int* __restrict__ batch,
    const float* __restrict__ Wn, const float* __restrict__ bn,
    const float* __restrict__ gn, const float* __restrict__ betan,
    const float* __restrict__ Gn, const float* __restrict__ abarN,
    float* __restrict__ Qws, int* __restrict__ validws,
    float* __restrict__ outV, int N)
{
  __shared__ float smem[256 * 8];      // 8 KB: per-thread row of 8 floats

  int lane = threadIdx.x & 63;
  int wave = threadIdx.x >> 6;
  int base = blockIdx.x * 256 + wave * 64;
  int i = base + lane;
  bool live = (i < N);
  int ic = live ? i : (N - 1);

  int im1 = (ic >= 1) ? ic - 1 : 0;
  int ip1 = (ic + 1 < N) ? ic + 1 : N - 1;
  int ip2 = (ic + 2 < N) ? ic + 2 : N - 1;

  V3 xm1 = v3(X[3*im1], X[3*im1+1], X[3*im1+2]);
  V3 x0  = v3(X[3*ic ], X[3*ic +1], X[3*ic +2]);
  V3 xp1 = v3(X[3*ip1], X[3*ip1+1], X[3*ip1+2]);
  V3 xp2 = v3(X[3*ip2], X[3*ip2+1], X[3*ip2+2]);

  int b0 = batch[ic];
  bool bnd_i  = (ic >= 1)    && (batch[ic - 1] != b0);
  bool bnd_i1 = (ic + 1 < N) && (batch[ic + 1] != b0);
  bool bnd_i2 = (ic + 2 < N) && (batch[ic + 2] != batch[ic + 1]);

  bool bad_d = bnd_i || bnd_i1 || bnd_i2 || (ic == 0) || (ic >= N - 2);
  bool bad_a = bnd_i || bnd_i1 || (ic == 0) || (ic == N - 1);

  V3 u0 = vunit(vsub(x0,  xm1));   // U[i-1]
  V3 u1 = vunit(vsub(xp1, x0 ));   // U[i]
  V3 u2 = vunit(vsub(xp2, xp1));   // U[i+1]
  V3 c1 = vunit(vcross(u0, u1));
  V3 c2 = vunit(vcross(u1, u2));

  float cosd = vdot(c1, c2);
  cosd = fminf(fmaxf(cosd, -1.0f + 1e-6f), 1.0f - 1e-6f);
  float sd = vdot(c2, u0);
  float f0, f1;
  if (bad_d)          { f0 = 0.f; f1 = 0.f; }
  else {
    float sg = sgnf(sd);
    if (sg == 0.f)    { f0 = 0.f; f1 = 1.f; }
    else              { f0 = sg * sqrtf(fmaxf(1.f - cosd * cosd, 0.f)); f1 = cosd; }
  }

  V3 d0 = vunit(vsub(xm1, x0));
  V3 d1 = vunit(vsub(xp1, x0));
  float cosa = vdot(d0, d1);
  float sina = sqrtf(fmaxf(1.0f - cosa * cosa + 1e-6f, 0.f));
  float f2 = bad_a ? 0.f : sina;
  float f3 = bad_a ? 0.f : cosa;

  // local frame Q (columns: bvec, nvec, bvec x nvec), zeroed when bad_a
  V3 bv = vunit(vsub(u0, u1));
  V3 nv = c1;                       // == unit(cross(u0,u1))
  V3 tv = vcross(bv, nv);
  float q[9];
  if (bad_a) {
    #pragma unroll
    for (int k = 0; k < 9; ++k) q[k] = 0.f;
  } else {
    q[0]=bv.x; q[1]=nv.x; q[2]=tv.x;
    q[3]=bv.y; q[4]=nv.y; q[5]=tv.y;
    q[6]=bv.z; q[7]=nv.z; q[8]=tv.z;
  }
  if (live) {
    f32x4* qp = (f32x4*)(Qws + (size_t)i * 12);
    f32x4 ca; ca.x=q[0]; ca.y=q[1]; ca.z=q[2]; ca.w=q[3];
    f32x4 cb; cb.x=q[4]; cb.y=q[5]; cb.z=q[6]; cb.w=q[7];
    f32x4 cc; cc.x=q[8]; cc.y=x0.x; cc.z=x0.y; cc.w=x0.z;
    qp[0] = ca; qp[1] = cb; qp[2] = cc;
    validws[i] = bad_a ? 0 : 1;
  }

  // analytic LN stats: fa = [f0..f3, 1]
  float fa[5] = { f0, f1, f2, f3, 1.0f };
  float mmean = 0.f;
  #pragma unroll
  for (int k = 0; k < 5; ++k) mmean = fmaf(fa[k], abarN[k], mmean);
  float E2 = 0.f;
  #pragma unroll
  for (int ii = 0; ii < 5; ++ii) {
    float ti = 0.f;
    #pragma unroll
    for (int jj = 0; jj < 5; ++jj) ti = fmaf(Gn[ii * 5 + jj], fa[jj], ti);
    E2 = fmaf(fa[ii], ti, E2);
  }
  float var  = fmaxf(E2 - mmean * mmean, 0.f);
  float rstd = rsqrtf(var + 1e-5f);

  // stage broadcast payload: [f0,f1,f2,f3,mean,rstd,0,0] per thread (2x b128 writes)
  {
    f32x4* rowp = (f32x4*)(smem + (int)threadIdx.x * 8);
    f32x4 v0; v0.x = f0; v0.y = f1; v0.z = f2; v0.w = f3;
    f32x4 v1; v1.x = mmean; v1.y = rstd; v1.z = 0.f; v1.w = 0.f;
    rowp[0] = v0; rowp[1] = v1;
  }

  // per-lane output column pair (2*lane, 2*lane+1), packed fp32
  f32x2 W2[4];
  #pragma unroll
  for (int k = 0; k < 4; ++k) W2[k] = *(const f32x2*)(Wn + k * 128 + 2 * lane);
  f32x2 b2 = *(const f32x2*)(bn    + 2 * lane);
  f32x2 g2 = *(const f32x2*)(gn    + 2 * lane);
  f32x2 e2 = *(const f32x2*)(betan + 2 * lane);

  __syncthreads();

  int nIt = N - base; nIt = (nIt > 64) ? 64 : nIt;
  const float* rp = smem + (wave * 64) * 8;
  float* op = outV + (size_t)base * 128 + 2 * lane;
  #pragma unroll 2
  for (int t = 0; t < nIt; ++t) {
    f32x4 v0 = *(const f32x4*)(rp + 0);
    f32x4 v1 = *(const f32x4*)(rp + 4);
    float bm = v1.x, br = v1.y;
    f32x2 acc = b2;
    f32x2 s0 = v0.x, s1 = v0.y, s2 = v0.z, s3 = v0.w;
    acc = __builtin_elementwise_fma(s0, W2[0], acc);
    acc = __builtin_elementwise_fma(s1, W2[1], acc);
    acc = __builtin_elementwise_fma(s2, W2[2], acc);
    acc = __builtin_elementwise_fma(s3, W2[3], acc);
    f32x2 out;
    out.x = (acc.x - bm) * br * g2.x + e2.x;
    out.y = (acc.y - bm) * br * g2.y + e2.y;
    *(f32x2*)op = out;
    rp += 8; op += 128;
  }
}

// ---------- edge kernel ----------
// Phase 1 (lane = edge): vectorized node-record gathers, compute f[23] + LN stats,
//   stage {f[0..22], mean, rstd} into LDS rows of stride 28 floats.
// Phase 2 (half-wave = edge, lane = column QUAD): 2 edges per wave-iteration, so
//   each uniform ds_read_b128 broadcast serves TWO edges (halves LDS-pipe traffic,
//   the measured bottleneck). 23 f32x4 FMAs -> 46 v_pk_fma_f32 per 2 edges (same
//   FLOPs as before), one coalesced dwordx4 store per 512B row-half.
__global__ __launch_bounds__(256, 3) void edge_kernel(
    const int* __restrict__ eidx,
    const float* __restrict__ We, const float* __restrict__ be,
    const float* __restrict__ ge, const float* __restrict__ betae,
    const float* __restrict__ Qws, const int* __restrict__ validws,
    const float* __restrict__ Ge, const float* __restrict__ abarE,
    float* __restrict__ outE, int N, int E)
{
  __shared__ float smem[256 * 28];       // 28 KB: 256 rows x 28 floats (25 used)

  int lane = threadIdx.x & 63;
  int wave = threadIdx.x >> 6;
  int base = blockIdx.x * 256 + wave * 64;
  int e = base + lane;
  int ec = (e < E) ? e : (E - 1);

  int s = eidx[ec];
  int t = eidx[E + ec];

  const f32x4* sp = (const f32x4*)(Qws + (size_t)s * 12);
  const f32x4* tp = (const f32x4*)(Qws + (size_t)t * 12);
  f32x4 sA = sp[0], sB = sp[1], sC = sp[2];
  f32x4 tA = tp[0], tB = tp[1], tC = tp[2];

  float Qs[9] = { sA.x, sA.y, sA.z, sA.w, sB.x, sB.y, sB.z, sB.w, sC.x };
  float Qt[9] = { tA.x, tA.y, tA.z, tA.w, tB.x, tB.y, tB.z, tB.w, tC.x };
  float Xs0 = sC.y, Xs1 = sC.z, Xs2 = sC.w;
  float Xt0 = tC.y, Xt1 = tC.z, Xt2 = tC.w;
  int ok = validws[s] & validws[t];

  // R = Qt^T * Qs ;  R[i][k] = sum_j Qt[3j+i]*Qs[3j+k]
  float R[9];
  #pragma unroll
  for (int i = 0; i < 3; ++i) {
    #pragma unroll
    for (int k = 0; k < 3; ++k) {
      R[3*i+k] = Qt[i] * Qs[k] + Qt[3+i] * Qs[3+k] + Qt[6+i] * Qs[6+k];
    }
  }

  float Rxx = R[0], Ryy = R[4], Rzz = R[8];
  float m0 = 0.5f * sqrtf(fabsf(1.f + Rxx - Ryy - Rzz));
  float m1 = 0.5f * sqrtf(fabsf(1.f - Rxx + Ryy - Rzz));
  float m2 = 0.5f * sqrtf(fabsf(1.f - Rxx - Ryy + Rzz));
  float s0 = sgnf(R[7] - R[5]);   // R21 - R12
  float s1 = sgnf(R[2] - R[6]);   // R02 - R20
  float s2 = sgnf(R[3] - R[1]);   // R10 - R01
  float w  = 0.5f * sqrtf(fmaxf(1.f + Rxx + Ryy + Rzz, 0.f));
  float q0 = s0 * m0, q1 = s1 * m1, q2 = s2 * m2;
  float qn = fmaxf(sqrtf(q0*q0 + q1*q1 + q2*q2 + w*w), 1e-12f);
  float qinv = 1.0f / qn;
  float msk = ok ? 1.f : 0.f;

  float f[23];
  f[0] = q0 * qinv * msk; f[1] = q1 * qinv * msk;
  f[2] = q2 * qinv * msk; f[3] = w  * qinv * msk;

  float dx = Xs0 - Xt0, dy = Xs1 - Xt1, dz = Xs2 - Xt2;
  float d2 = dx*dx + dy*dy + dz*dz;
  float dist = sqrtf(d2 + 1e-6f);
  #pragma unroll
  for (int k = 0; k < 16; ++k) {
    float u = (dist - (float)k * (20.0f / 15.0f)) * 0.8f;
    f[4 + k] = __expf(-u * u);
  }
  float dn = fmaxf(sqrtf(d2), 1e-12f);
  float rinv = 1.0f / dn;
  float ux = dx * rinv, uy = dy * rinv, uz = dz * rinv;
  // direct = Qt^T * u  (Qt rows are zero when tgt invalid -> already masked)
  f[20] = Qt[0]*ux + Qt[3]*uy + Qt[6]*uz;
  f[21] = Qt[1]*ux + Qt[4]*uy + Qt[7]*uz;
  f[22] = Qt[2]*ux + Qt[5]*uy + Qt[8]*uz;

  // analytic LN stats (fa = [f, 1]); Ge/abarE loads are wave-uniform -> scalar path
  float mmean = abarE[23];
  #pragma unroll
  for (int k = 0; k < 23; ++k) mmean = fmaf(f[k], abarE[k], mmean);
  float E2 = 0.f;
  #pragma unroll
  for (int ii = 0; ii < 24; ++ii) {
    float fi = (ii < 23) ? f[ii] : 1.0f;
    float ti = 0.f;
    #pragma unroll
    for (int jj = 0; jj < 24; ++jj) {
      float fj = (jj < 23) ? f[jj] : 1.0f;
      ti = fmaf(Ge[ii * 24 + jj], fj, ti);
    }
    E2 = fmaf(fi, ti, E2);
  }
  float var  = fmaxf(E2 - mmean * mmean, 0.f);
  float rstd = rsqrtf(var + 1e-5f);

  // stage broadcast payload: 6 b128 + 1 b32 write into row of stride 28 floats
  {
    float* rowf = smem + (int)threadIdx.x * 28;
    f32x4* rowp = (f32x4*)rowf;
    f32x4 v;
    v.x = f[0];  v.y = f[1];  v.z = f[2];  v.w = f[3];  rowp[0] = v;
    v.x = f[4];  v.y = f[5];  v.z = f[6];  v.w = f[7];  rowp[1] = v;
    v.x = f[8];  v.y = f[9];  v.z = f[10]; v.w = f[11]; rowp[2] = v;
    v.x = f[12]; v.y = f[13]; v.z = f[14]; v.w = f[15]; rowp[3] = v;
    v.x = f[16]; v.y = f[17]; v.z = f[18]; v.w = f[19]; rowp[4] = v;
    v.x = f[20]; v.y = f[21]; v.z = f[22]; v.w = mmean; rowp[5] = v;
    rowf[24] = rstd;
  }

  // per-lane output column quad (issue loads before the barrier so they overlap it)
  int half = lane >> 5;          // which edge of the pair this half-wave handles
  int cq   = (lane & 31) * 4;    // first of 4 owned columns
  f32x4 Wc[23];
  #pragma unroll
  for (int k = 0; k < 23; ++k) Wc[k] = *(const f32x4*)(We + k * 128 + cq);
  f32x4 b4 = *(const f32x4*)(be    + cq);
  f32x4 g4 = *(const f32x4*)(ge    + cq);
  f32x4 e4 = *(const f32x4*)(betae + cq);

  __syncthreads();

  int nIt = E - base; nIt = (nIt > 64) ? 64 : nIt;
  const float* rp = smem + (wave * 64 + half) * 28;
  float* op = outE + (size_t)(base + half) * 128 + cq;
  for (int tt = 0; tt < 32; ++tt) {
    int rel = 2 * tt + half;
    if (rel >= nIt) break;
    f32x4 c0 = *(const f32x4*)(rp + 0);
    f32x4 c1 = *(const f32x4*)(rp + 4);
    f32x4 c2 = *(const f32x4*)(rp + 8);
    f32x4 c3 = *(const f32x4*)(rp + 12);
    f32x4 c4 = *(const f32x4*)(rp + 16);
    f32x4 c5 = *(const f32x4*)(rp + 20);
    float br = rp[24];
    float bm = c5.w;
    float fs[23] = { c0.x, c0.y, c0.z, c0.w,
                     c1.x, c1.y, c1.z, c1.w,
                     c2.x, c2.y, c2.z, c2.w,
                     c3.x, c3.y, c3.z, c3.w,
                     c4.x, c4.y, c4.z, c4.w,
                     c5.x, c5.y, c5.z };
    f32x4 acc = b4;
    #pragma unroll
    for (int k = 0; k < 23; ++k) {
      f32x4 sv = fs[k];                              // splat -> 2x v_pk_fma_f32
      acc = __builtin_elementwise_fma(sv, Wc[k], acc);
    }
    f32x4 out;
    out.x = (acc.x - bm) * br * g4.x + e4.x;
    out.y = (acc.y - bm) * br * g4.y + e4.y;
    out.z = (acc.z - bm) * br * g4.z + e4.z;
    out.w = (acc.w - bm) * br * g4.w + e4.w;
    *(f32x4*)op = out;
    rp += 2 * 28; op += 2 * 128;
  }
}

// ---------- launcher ----------
extern "C" void kernel_launch(void* const* d_in, const int* in_sizes, int n_in,
                              void* d_out, int out_size, void* d_ws, size_t ws_size,
                              hipStream_t stream)
{
  const float* X     = (const float*)d_in[0];
  const int*   batch = (const int*)  d_in[1];
  const int*   eidx  = (const int*)  d_in[2];
  const float* Wn    = (const float*)d_in[3];
  const float* bn    = (const float*)d_in[4];
  const float* gn    = (const float*)d_in[5];
  const float* betan = (const float*)d_in[6];
  const float* We    = (const float*)d_in[7];
  const float* be    = (const float*)d_in[8];
  const float* ge    = (const float*)d_in[9];
  const float* betae = (const float*)d_in[10];

  int N = in_sizes[0] / 3;
  int E = in_sizes[2] / 2;

  float* ws      = (float*)d_ws;
  float* Qws     = ws;                                  // N*12 floats (16B-aligned rows)
  int*   validws = (int*)(ws + (size_t)N * 12);         // N ints
  float* Ge      = ws + (size_t)N * 12 + N;             // 576
  float* abarE   = Ge + 576;                            // 24
  float* Gn      = abarE + 24;                          // 25
  float* abarN   = Gn + 25;                             // 5

  float* outV = (float*)d_out;
  float* outE = outV + (size_t)N * 128;

  hipLaunchKernelGGL(setup_gram, dim3(1), dim3(640), 0, stream,
                     Wn, bn, We, be, Ge, abarE, Gn, abarN);

  int nblocks = (N + 255) / 256;
  hipLaunchKernelGGL(node_kernel, dim3(nblocks), dim3(256), 0, stream,
                     X, batch, Wn, bn, gn, betan, Gn, abarN, Qws, validws, outV, N);

  int eblocks = (E + 255) / 256;
  hipLaunchKernelGGL(edge_kernel, dim3(eblocks), dim3(256), 0, stream,
                     eidx, We, be, ge, betae, Qws, validws, Ge, abarE, outE, N, E);
}

// Round 4
// 617.168 us; speedup vs baseline: 1.1711x; 1.0142x over previous
//
#include <hip/hip_runtime.h>
#include <math.h>

typedef __attribute__((ext_vector_type(2))) float f32x2;
typedef __attribute__((ext_vector_type(4))) float f32x4;

// ---------- small vector helpers ----------
struct V3 { float x, y, z; };
__device__ __forceinline__ V3 v3(float a, float b, float c){ V3 r; r.x=a; r.y=b; r.z=c; return r; }
__device__ __forceinline__ V3 vsub(V3 a, V3 b){ return v3(a.x-b.x, a.y-b.y, a.z-b.z); }
__device__ __forceinline__ float vdot(V3 a, V3 b){ return a.x*b.x + a.y*b.y + a.z*b.z; }
__device__ __forceinline__ V3 vcross(V3 a, V3 b){
  return v3(a.y*b.z - a.z*b.y, a.z*b.x - a.x*b.z, a.x*b.y - a.y*b.x);
}
__device__ __forceinline__ V3 vunit(V3 a){            // reference _normalize: x / max(|x|, 1e-12)
  float n = sqrtf(vdot(a,a));
  float inv = 1.0f / fmaxf(n, 1e-12f);
  return v3(a.x*inv, a.y*inv, a.z*inv);
}
__device__ __forceinline__ float sgnf(float x){ return (x > 0.f) ? 1.f : ((x < 0.f) ? -1.f : 0.f); }

// ---------- setup: Gram matrices for analytic LayerNorm stats ----------
__global__ void setup_gram(const float* __restrict__ Wn, const float* __restrict__ bn,
                           const float* __restrict__ We, const float* __restrict__ be,
                           float* __restrict__ Ge, float* __restrict__ abarE,
                           float* __restrict__ Gn, float* __restrict__ abarN)
{
  int tid = threadIdx.x;
  if (tid < 576) {
    int i = tid / 24, j = tid % 24;
    const float* ai = (i < 23) ? (We + i * 128) : be;
    const float* aj = (j < 23) ? (We + j * 128) : be;
    float s = 0.f;
    for (int c = 0; c < 128; ++c) s += ai[c] * aj[c];
    Ge[tid] = s * (1.0f / 128.0f);
  } else if (tid < 601) {
    int t = tid - 576; int i = t / 5, j = t % 5;
    const float* ai = (i < 4) ? (Wn + i * 128) : bn;
    const float* aj = (j < 4) ? (Wn + j * 128) : bn;
    float s = 0.f;
    for (int c = 0; c < 128; ++c) s += ai[c] * aj[c];
    Gn[t] = s * (1.0f / 128.0f);
  } else if (tid < 625) {
    int k = tid - 601;
    const float* a = (k < 23) ? (We + k * 128) : be;
    float s = 0.f;
    for (int c = 0; c < 128; ++c) s += a[c];
    abarE[k] = s * (1.0f / 128.0f);
  } else if (tid < 630) {
    int k = tid - 625;
    const float* a = (k < 4) ? (Wn + k * 128) : bn;
    float s = 0.f;
    for (int c = 0; c < 128; ++c) s += a[c];
    abarN[k] = s * (1.0f / 128.0f);
  }
}

// ---------- node kernel: h_V + stage 12-float node records [Q(9), x, y, z] ----------
// Validity is encoded in the record itself: Q's first column is exactly unit when
// valid and exactly zero when invalid (bad_a zeroes all 9 entries).
__global__ __launch_bounds__(256, 4) void node_kernel(
    const float* __restrict__ X, const int* __restrict__ batch,
    const float* __restrict__ Wn, const float* __restrict__ bn,
    const float* __restrict__ gn, const float* __restrict__ betan,
    const float* __restrict__ Gn, const float* __restrict__ abarN,
    float* __restrict__ Qws,
    float* __restrict__ outV, int N)
{
  __shared__ float smem[256 * 8];      // 8 KB: per-thread row of 8 floats

  int lane = threadIdx.x & 63;
  int wave = threadIdx.x >> 6;
  int base = blockIdx.x * 256 + wave * 64;
  int i = base + lane;
  bool live = (i < N);
  int ic = live ? i : (N - 1);

  int im1 = (ic >= 1) ? ic - 1 : 0;
  int ip1 = (ic + 1 < N) ? ic + 1 : N - 1;
  int ip2 = (ic + 2 < N) ? ic + 2 : N - 1;

  V3 xm1 = v3(X[3*im1], X[3*im1+1], X[3*im1+2]);
  V3 x0  = v3(X[3*ic ], X[3*ic +1], X[3*ic +2]);
  V3 xp1 = v3(X[3*ip1], X[3*ip1+1], X[3*ip1+2]);
  V3 xp2 = v3(X[3*ip2], X[3*ip2+1], X[3*ip2+2]);

  int b0 = batch[ic];
  bool bnd_i  = (ic >= 1)    && (batch[ic - 1] != b0);
  bool bnd_i1 = (ic + 1 < N) && (batch[ic + 1] != b0);
  bool bnd_i2 = (ic + 2 < N) && (batch[ic + 2] != batch[ic + 1]);

  bool bad_d = bnd_i || bnd_i1 || bnd_i2 || (ic == 0) || (ic >= N - 2);
  bool bad_a = bnd_i || bnd_i1 || (ic == 0) || (ic == N - 1);

  V3 u0 = vunit(vsub(x0,  xm1));   // U[i-1]
  V3 u1 = vunit(vsub(xp1, x0 ));   // U[i]
  V3 u2 = vunit(vsub(xp2, xp1));   // U[i+1]
  V3 c1 = vunit(vcross(u0, u1));
  V3 c2 = vunit(vcross(u1, u2));

  float cosd = vdot(c1, c2);
  cosd = fminf(fmaxf(cosd, -1.0f + 1e-6f), 1.0f - 1e-6f);
  float sd = vdot(c2, u0);
  float f0, f1;
  if (bad_d)          { f0 = 0.f; f1 = 0.f; }
  else {
    float sg = sgnf(sd);
    if (sg == 0.f)    { f0 = 0.f; f1 = 1.f; }
    else              { f0 = sg * sqrtf(fmaxf(1.f - cosd * cosd, 0.f)); f1 = cosd; }
  }

  V3 d0 = vunit(vsub(xm1, x0));
  V3 d1 = vunit(vsub(xp1, x0));
  float cosa = vdot(d0, d1);
  float sina = sqrtf(fmaxf(1.0f - cosa * cosa + 1e-6f, 0.f));
  float f2 = bad_a ? 0.f : sina;
  float f3 = bad_a ? 0.f : cosa;

  // local frame Q (columns: bvec, nvec, bvec x nvec), zeroed when bad_a
  V3 bv = vunit(vsub(u0, u1));
  V3 nv = c1;                       // == unit(cross(u0,u1))
  V3 tv = vcross(bv, nv);
  float q[9];
  if (bad_a) {
    #pragma unroll
    for (int k = 0; k < 9; ++k) q[k] = 0.f;
  } else {
    q[0]=bv.x; q[1]=nv.x; q[2]=tv.x;
    q[3]=bv.y; q[4]=nv.y; q[5]=tv.y;
    q[6]=bv.z; q[7]=nv.z; q[8]=tv.z;
  }
  if (live) {
    f32x4* qp = (f32x4*)(Qws + (size_t)i * 12);
    f32x4 ca; ca.x=q[0]; ca.y=q[1]; ca.z=q[2]; ca.w=q[3];
    f32x4 cb; cb.x=q[4]; cb.y=q[5]; cb.z=q[6]; cb.w=q[7];
    f32x4 cc; cc.x=q[8]; cc.y=x0.x; cc.z=x0.y; cc.w=x0.z;
    qp[0] = ca; qp[1] = cb; qp[2] = cc;
  }

  // analytic LN stats: fa = [f0..f3, 1]
  float fa[5] = { f0, f1, f2, f3, 1.0f };
  float mmean = 0.f;
  #pragma unroll
  for (int k = 0; k < 5; ++k) mmean = fmaf(fa[k], abarN[k], mmean);
  float E2 = 0.f;
  #pragma unroll
  for (int ii = 0; ii < 5; ++ii) {
    float ti = 0.f;
    #pragma unroll
    for (int jj = 0; jj < 5; ++jj) ti = fmaf(Gn[ii * 5 + jj], fa[jj], ti);
    E2 = fmaf(fa[ii], ti, E2);
  }
  float var  = fmaxf(E2 - mmean * mmean, 0.f);
  float rstd = rsqrtf(var + 1e-5f);

  // stage broadcast payload: [f0,f1,f2,f3,mean,rstd,0,0] per thread (2x b128 writes)
  {
    f32x4* rowp = (f32x4*)(smem + (int)threadIdx.x * 8);
    f32x4 v0; v0.x = f0; v0.y = f1; v0.z = f2; v0.w = f3;
    f32x4 v1; v1.x = mmean; v1.y = rstd; v1.z = 0.f; v1.w = 0.f;
    rowp[0] = v0; rowp[1] = v1;
  }

  // per-lane output column pair (2*lane, 2*lane+1), packed fp32
  f32x2 W2[4];
  #pragma unroll
  for (int k = 0; k < 4; ++k) W2[k] = *(const f32x2*)(Wn + k * 128 + 2 * lane);
  f32x2 b2 = *(const f32x2*)(bn    + 2 * lane);
  f32x2 g2 = *(const f32x2*)(gn    + 2 * lane);
  f32x2 e2 = *(const f32x2*)(betan + 2 * lane);

  __syncthreads();

  int nIt = N - base; nIt = (nIt > 64) ? 64 : nIt;
  const float* rp = smem + (wave * 64) * 8;
  float* op = outV + (size_t)base * 128 + 2 * lane;
  #pragma unroll 2
  for (int t = 0; t < nIt; ++t) {
    f32x4 v0 = *(const f32x4*)(rp + 0);
    f32x4 v1 = *(const f32x4*)(rp + 4);
    float bm = v1.x, br = v1.y;
    f32x2 acc = b2;
    f32x2 s0 = v0.x, s1 = v0.y, s2 = v0.z, s3 = v0.w;
    acc = __builtin_elementwise_fma(s0, W2[0], acc);
    acc = __builtin_elementwise_fma(s1, W2[1], acc);
    acc = __builtin_elementwise_fma(s2, W2[2], acc);
    acc = __builtin_elementwise_fma(s3, W2[3], acc);
    f32x2 out;
    out.x = (acc.x - bm) * br * g2.x + e2.x;
    out.y = (acc.y - bm) * br * g2.y + e2.y;
    __builtin_nontemporal_store(out, (f32x2*)op);   // stream past L2
    rp += 8; op += 128;
  }
}

// ---------- edge kernel ----------
// Phase 1 (lane = edge): two 48B record gathers (cache-resident table — output is
//   streamed non-temporally so L2 keeps the table), compute f[23] + LN stats,
//   stage into LDS rows of stride 28 floats. Validity from record column norm.
// Phase 2 (half-wave = edge, lane = column QUAD): uniform ds_read_b128 broadcasts
//   serve two edges each; 23 f32x4 FMAs; one nt dwordx4 store per row-half.
__global__ __launch_bounds__(256, 3) void edge_kernel(
    const int* __restrict__ eidx,
    const float* __restrict__ We, const float* __restrict__ be,
    const float* __restrict__ ge, const float* __restrict__ betae,
    const float* __restrict__ Qws,
    const float* __restrict__ Ge, const float* __restrict__ abarE,
    float* __restrict__ outE, int N, int E)
{
  __shared__ float smem[256 * 28];       // 28 KB: 256 rows x 28 floats (25 used)

  int lane = threadIdx.x & 63;
  int wave = threadIdx.x >> 6;
  int base = blockIdx.x * 256 + wave * 64;
  int e = base + lane;
  int ec = (e < E) ? e : (E - 1);

  int s = __builtin_nontemporal_load(eidx + ec);
  int t = __builtin_nontemporal_load(eidx + E + ec);

  const f32x4* sp = (const f32x4*)(Qws + (size_t)s * 12);
  const f32x4* tp = (const f32x4*)(Qws + (size_t)t * 12);
  f32x4 sA = sp[0], sB = sp[1], sC = sp[2];
  f32x4 tA = tp[0], tB = tp[1], tC = tp[2];

  float Qs[9] = { sA.x, sA.y, sA.z, sA.w, sB.x, sB.y, sB.z, sB.w, sC.x };
  float Qt[9] = { tA.x, tA.y, tA.z, tA.w, tB.x, tB.y, tB.z, tB.w, tC.x };
  float Xs0 = sC.y, Xs1 = sC.z, Xs2 = sC.w;
  float Xt0 = tC.y, Xt1 = tC.z, Xt2 = tC.w;

  // validity from the record: first column of Q is exactly unit (valid) or zero
  float sv2 = Qs[0]*Qs[0] + Qs[3]*Qs[3] + Qs[6]*Qs[6];
  float tv2 = Qt[0]*Qt[0] + Qt[3]*Qt[3] + Qt[6]*Qt[6];
  float msk = (sv2 > 0.5f && tv2 > 0.5f) ? 1.f : 0.f;

  // R = Qt^T * Qs ;  R[i][k] = sum_j Qt[3j+i]*Qs[3j+k]
  float R[9];
  #pragma unroll
  for (int i = 0; i < 3; ++i) {
    #pragma unroll
    for (int k = 0; k < 3; ++k) {
      R[3*i+k] = Qt[i] * Qs[k] + Qt[3+i] * Qs[3+k] + Qt[6+i] * Qs[6+k];
    }
  }

  float Rxx = R[0], Ryy = R[4], Rzz = R[8];
  float m0 = 0.5f * sqrtf(fabsf(1.f + Rxx - Ryy - Rzz));
  float m1 = 0.5f * sqrtf(fabsf(1.f - Rxx + Ryy - Rzz));
  float m2 = 0.5f * sqrtf(fabsf(1.f - Rxx - Ryy + Rzz));
  float s0 = sgnf(R[7] - R[5]);   // R21 - R12
  float s1 = sgnf(R[2] - R[6]);   // R02 - R20
  float s2 = sgnf(R[3] - R[1]);   // R10 - R01
  float w  = 0.5f * sqrtf(fmaxf(1.f + Rxx + Ryy + Rzz, 0.f));
  float q0 = s0 * m0, q1 = s1 * m1, q2 = s2 * m2;
  float qn = fmaxf(sqrtf(q0*q0 + q1*q1 + q2*q2 + w*w), 1e-12f);
  float qinv = 1.0f / qn;

  float f[23];
  f[0] = q0 * qinv * msk; f[1] = q1 * qinv * msk;
  f[2] = q2 * qinv * msk; f[3] = w  * qinv * msk;

  float dx = Xs0 - Xt0, dy = Xs1 - Xt1, dz = Xs2 - Xt2;
  float d2 = dx*dx + dy*dy + dz*dz;
  float dist = sqrtf(d2 + 1e-6f);
  #pragma unroll
  for (int k = 0; k < 16; ++k) {
    float u = (dist - (float)k * (20.0f / 15.0f)) * 0.8f;
    f[4 + k] = __expf(-u * u);
  }
  float dn = fmaxf(sqrtf(d2), 1e-12f);
  float rinv = 1.0f / dn;
  float ux = dx * rinv, uy = dy * rinv, uz = dz * rinv;
  // direct = Qt^T * u  (Qt rows are zero when tgt invalid -> already masked)
  f[20] = Qt[0]*ux + Qt[3]*uy + Qt[6]*uz;
  f[21] = Qt[1]*ux + Qt[4]*uy + Qt[7]*uz;
  f[22] = Qt[2]*ux + Qt[5]*uy + Qt[8]*uz;

  // analytic LN stats (fa = [f, 1]); Ge/abarE loads are wave-uniform -> scalar path
  float mmean = abarE[23];
  #pragma unroll
  for (int k = 0; k < 23; ++k) mmean = fmaf(f[k], abarE[k], mmean);
  float E2 = 0.f;
  #pragma unroll
  for (int ii = 0; ii < 24; ++ii) {
    float fi = (ii < 23) ? f[ii] : 1.0f;
    float ti = 0.f;
    #pragma unroll
    for (int jj = 0; jj < 24; ++jj) {
      float fj = (jj < 23) ? f[jj] : 1.0f;
      ti = fmaf(Ge[ii * 24 + jj], fj, ti);
    }
    E2 = fmaf(fi, ti, E2);
  }
  float var  = fmaxf(E2 - mmean * mmean, 0.f);
  float rstd = rsqrtf(var + 1e-5f);

  // stage broadcast payload: 6 b128 + 1 b32 write into row of stride 28 floats
  {
    float* rowf = smem + (int)threadIdx.x * 28;
    f32x4* rowp = (f32x4*)rowf;
    f32x4 v;
    v.x = f[0];  v.y = f[1];  v.z = f[2];  v.w = f[3];  rowp[0] = v;
    v.x = f[4];  v.y = f[5];  v.z = f[6];  v.w = f[7];  rowp[1] = v;
    v.x = f[8];  v.y = f[9];  v.z = f[10]; v.w = f[11]; rowp[2] = v;
    v.x = f[12]; v.y = f[13]; v.z = f[14]; v.w = f[15]; rowp[3] = v;
    v.x = f[16]; v.y = f[17]; v.z = f[18]; v.w = f[19]; rowp[4] = v;
    v.x = f[20]; v.y = f[21]; v.z = f[22]; v.w = mmean; rowp[5] = v;
    rowf[24] = rstd;
  }

  // per-lane output column quad (issue loads before the barrier so they overlap it)
  int half = lane >> 5;          // which edge of the pair this half-wave handles
  int cq   = (lane & 31) * 4;    // first of 4 owned columns
  f32x4 Wc[23];
  #pragma unroll
  for (int k = 0; k < 23; ++k) Wc[k] = *(const f32x4*)(We + k * 128 + cq);
  f32x4 b4 = *(const f32x4*)(be    + cq);
  f32x4 g4 = *(const f32x4*)(ge    + cq);
  f32x4 e4 = *(const f32x4*)(betae + cq);

  __syncthreads();

  int nIt = E - base; nIt = (nIt > 64) ? 64 : nIt;
  const float* rp = smem + (wave * 64 + half) * 28;
  float* op = outE + (size_t)(base + half) * 128 + cq;
  for (int tt = 0; tt < 32; ++tt) {
    int rel = 2 * tt + half;
    if (rel >= nIt) break;
    f32x4 c0 = *(const f32x4*)(rp + 0);
    f32x4 c1 = *(const f32x4*)(rp + 4);
    f32x4 c2 = *(const f32x4*)(rp + 8);
    f32x4 c3 = *(const f32x4*)(rp + 12);
    f32x4 c4 = *(const f32x4*)(rp + 16);
    f32x4 c5 = *(const f32x4*)(rp + 20);
    float br = rp[24];
    float bm = c5.w;
    float fs[23] = { c0.x, c0.y, c0.z, c0.w,
                     c1.x, c1.y, c1.z, c1.w,
                     c2.x, c2.y, c2.z, c2.w,
                     c3.x, c3.y, c3.z, c3.w,
                     c4.x, c4.y, c4.z, c4.w,
                     c5.x, c5.y, c5.z };
    f32x4 acc = b4;
    #pragma unroll
    for (int k = 0; k < 23; ++k) {
      f32x4 sv = fs[k];                              // splat -> 2x v_pk_fma_f32
      acc = __builtin_elementwise_fma(sv, Wc[k], acc);
    }
    f32x4 out;
    out.x = (acc.x - bm) * br * g4.x + e4.x;
    out.y = (acc.y - bm) * br * g4.y + e4.y;
    out.z = (acc.z - bm) * br * g4.z + e4.z;
    out.w = (acc.w - bm) * br * g4.w + e4.w;
    __builtin_nontemporal_store(out, (f32x4*)op);    // stream past L2, keep Qws resident
    rp += 2 * 28; op += 2 * 128;
  }
}

// ---------- launcher ----------
extern "C" void kernel_launch(void* const* d_in, const int* in_sizes, int n_in,
                              void* d_out, int out_size, void* d_ws, size_t ws_size,
                              hipStream_t stream)
{
  const float* X     = (const float*)d_in[0];
  const int*   batch = (const int*)  d_in[1];
  const int*   eidx  = (const int*)  d_in[2];
  const float* Wn    = (const float*)d_in[3];
  const float* bn    = (const float*)d_in[4];
  const float* gn    = (const float*)d_in[5];
  const float* betan = (const float*)d_in[6];
  const float* We    = (const float*)d_in[7];
  const float* be    = (const float*)d_in[8];
  const float* ge    = (const float*)d_in[9];
  const float* betae = (const float*)d_in[10];

  int N = in_sizes[0] / 3;
  int E = in_sizes[2] / 2;

  float* ws      = (float*)d_ws;
  float* Qws     = ws;                                  // N*12 floats (16B-aligned rows)
  float* Ge      = ws + (size_t)N * 12;                 // 576
  float* abarE   = Ge + 576;                            // 24
  float* Gn      = abarE + 24;                          // 25
  float* abarN   = Gn + 25;                             // 5

  float* outV = (float*)d_out;
  float* outE = outV + (size_t)N * 128;

  hipLaunchKernelGGL(setup_gram, dim3(1), dim3(640), 0, stream,
                     Wn, bn, We, be, Ge, abarE, Gn, abarN);

  int nblocks = (N + 255) / 256;
  hipLaunchKernelGGL(node_kernel, dim3(nblocks), dim3(256), 0, stream,
                     X, batch, Wn, bn, gn, betan, Gn, abarN, Qws, outV, N);

  int eblocks = (E + 255) / 256;
  hipLaunchKernelGGL(edge_kernel, dim3(eblocks), dim3(256), 0, stream,
                     eidx, We, be, ge, betae, Qws, Ge, abarE, outE, N, E);
}